// Round 1
// baseline (245.364 us; speedup 1.0000x reference)
//
#include <hip/hip_runtime.h>

#define WIN      60
#define OFFSET_D 40
#define TRUNC    21
#define EPS      1e-8f
#define BB       64
#define TT       4000
#define KK       100
#define TK       (TT*KK)          // 400000
#define TOTAL    (BB*TK)          // 25,600,000

// ---------------- kernel 1: masked sum of -log(clip(1-X)) over all (b,t,k) with t < lengths[b]
__global__ void neg_sum_kernel(const float* __restrict__ X,
                               const int* __restrict__ lengths,
                               double* __restrict__ acc) {
    float local = 0.0f;
    const int tid      = blockIdx.x * blockDim.x + threadIdx.x;
    const int nthreads = gridDim.x * blockDim.x;

    for (int n = tid * 4; n < TOTAL; n += nthreads * 4) {
        const int b  = n / TK;              // magic-mul div
        const int m  = n - b * TK;
        const int t0 = m / KK;
        const int len = lengths[b];
        if (t0 >= len) continue;            // whole float4 in an invalid row: skip the load

        const float4 v = *reinterpret_cast<const float4*>(X + n);
        const int t3 = (m + 3) / KK;
        if (t3 < len) {                     // common case: all 4 valid
            local -= __logf(fminf(fmaxf(1.0f - v.x, EPS), 1.0f));
            local -= __logf(fminf(fmaxf(1.0f - v.y, EPS), 1.0f));
            local -= __logf(fminf(fmaxf(1.0f - v.z, EPS), 1.0f));
            local -= __logf(fminf(fmaxf(1.0f - v.w, EPS), 1.0f));
        } else {                            // straddles the length boundary (rare)
            const float e[4] = {v.x, v.y, v.z, v.w};
            #pragma unroll
            for (int i = 0; i < 4; ++i) {
                const int ti = (m + i) / KK;
                if (ti < len) local -= __logf(fminf(fmaxf(1.0f - e[i], EPS), 1.0f));
            }
        }
    }

    // wave64 reduction, then one f64 atomic per wave
    #pragma unroll
    for (int off = 32; off > 0; off >>= 1) local += __shfl_down(local, off);
    if ((threadIdx.x & 63) == 0) atomicAdd(acc, (double)local);
}

// ---------------- kernel 2: per-batch positive term + target-window subtraction
__global__ void pos_kernel(const float* __restrict__ X,
                           const int* __restrict__ lengths,
                           const int* __restrict__ tgt,
                           const int* __restrict__ w_end,
                           double* __restrict__ acc) {
    __shared__ float wpad[80];   // wpad[p] = win[p-9], zero elsewhere (covers i+u, i<60, u<21)
    __shared__ float gn[TRUNC];

    const int b   = blockIdx.x;
    const int tid = threadIdx.x;  // 64 threads = 1 wave

    const int ts  = max(0, w_end[b] + OFFSET_D - WIN);
    const int len = lengths[b];
    const int te  = min(ts + WIN, len);
    const int Lw  = te - ts;
    const int tg  = tgt[b];

    wpad[tid] = 0.0f;
    if (tid < 16) wpad[64 + tid] = 0.0f;
    if (tid == 0) {
        // normalized truncated Gaussian, computed in f64 then stored f32
        double s = 0.0;
        for (int u = 0; u < TRUNC; ++u) { double x = (u - 10) / 9.0; s += exp(-0.5 * x * x); }
        for (int u = 0; u < TRUNC; ++u) { double x = (u - 10) / 9.0; gn[u] = (float)(exp(-0.5 * x * x) / s); }
    }
    __syncthreads();

    float sub = 0.0f;
    if (tid < WIN) {
        const float xw = X[(size_t)b * TK + (size_t)(ts + tid) * KK + tg];
        if (tid < Lw) {
            wpad[9 + tid] = xw;   // zero-padded ragged window
            sub = -__logf(fminf(fmaxf(1.0f - xw, EPS), 1.0f));
        }
    }
    __syncthreads();

    float cand = 0.0f;
    if (tid < WIN) {
        float s = 0.0f;
        #pragma unroll
        for (int u = 0; u < TRUNC; ++u) s += gn[u] * wpad[tid + u];
        s = fminf(fmaxf(s, EPS), 1.0f);
        cand = (tid < Lw) ? s : 0.0f;   // exclude out-of-window positions from max
    }

    #pragma unroll
    for (int off = 32; off > 0; off >>= 1) {
        sub += __shfl_down(sub, off);
        cand = fmaxf(cand, __shfl_down(cand, off));
    }
    if (tid == 0) {
        const float pos = -__logf(cand);
        atomicAdd(acc, (double)(pos - sub));
    }
}

// ---------------- kernel 3: finalize scalar
__global__ void finalize_kernel(const double* __restrict__ acc, float* __restrict__ out) {
    out[0] = (float)acc[0];
}

extern "C" void kernel_launch(void* const* d_in, const int* in_sizes, int n_in,
                              void* d_out, int out_size, void* d_ws, size_t ws_size,
                              hipStream_t stream) {
    const float* X       = (const float*)d_in[0];
    const int*   lengths = (const int*)d_in[1];
    const int*   tgt     = (const int*)d_in[2];
    const int*   w_end   = (const int*)d_in[3];
    float*       out     = (float*)d_out;
    double*      acc     = (double*)d_ws;

    hipMemsetAsync(acc, 0, sizeof(double), stream);
    neg_sum_kernel<<<2048, 256, 0, stream>>>(X, lengths, acc);
    pos_kernel<<<BB, 64, 0, stream>>>(X, lengths, tgt, w_end, acc);
    finalize_kernel<<<1, 1, 0, stream>>>(acc, out);
}

// Round 2
// 158.240 us; speedup vs baseline: 1.5506x; 1.5506x over previous
//
#include <hip/hip_runtime.h>

#define WIN      60
#define OFFSET_D 40
#define TRUNC    21
#define EPS      1e-8f
#define BB       64
#define TT       4000
#define KK       100
#define TK       (TT*KK)          // 400000 elements per batch
#define CH       50               // chunks per batch
#define CHUNK    (TK/CH)          // 8000 elements (multiple of 4*256? 8000/1024 -> ~7.8 iters/thread)
#define NB1      (BB*CH)          // 3200 partial slots for kernel 1
#define NPART    (NB1 + BB)       // + 64 pos-kernel slots

// ---------------- kernel 1: masked sum of -log(clip(1-X)), contiguous chunk per block
__global__ __launch_bounds__(256) void neg_sum_kernel(const float* __restrict__ X,
                                                      const int* __restrict__ lengths,
                                                      double* __restrict__ partials) {
    const int bid = blockIdx.x;
    const int b   = bid / CH;               // CH is compile-time const -> magic mul
    const int c   = bid - b * CH;
    const int s   = c * CHUNK;              // chunk start within row-set (multiple of 4)
    const int lenK = lengths[b] * KK;       // valid element count, always multiple of 4
    const int e   = min(s + CHUNK, lenK);

    float local = 0.0f;
    const float* __restrict__ base = X + (size_t)b * TK;

    #pragma unroll 4
    for (int m = s + (threadIdx.x << 2); m < e; m += 256 * 4) {
        const float4 v = *reinterpret_cast<const float4*>(base + m);
        local -= __logf(fminf(fmaxf(1.0f - v.x, EPS), 1.0f));
        local -= __logf(fminf(fmaxf(1.0f - v.y, EPS), 1.0f));
        local -= __logf(fminf(fmaxf(1.0f - v.z, EPS), 1.0f));
        local -= __logf(fminf(fmaxf(1.0f - v.w, EPS), 1.0f));
    }

    // wave64 shfl reduce, then cross-wave via LDS; one deterministic store per block
    #pragma unroll
    for (int off = 32; off > 0; off >>= 1) local += __shfl_down(local, off);
    __shared__ float wsum[4];
    if ((threadIdx.x & 63) == 0) wsum[threadIdx.x >> 6] = local;
    __syncthreads();
    if (threadIdx.x == 0)
        partials[bid] = (double)(wsum[0] + wsum[1] + wsum[2] + wsum[3]);
}

// ---------------- kernel 2: per-batch positive term + target-window subtraction
__global__ __launch_bounds__(64) void pos_kernel(const float* __restrict__ X,
                                                 const int* __restrict__ lengths,
                                                 const int* __restrict__ tgt,
                                                 const int* __restrict__ w_end,
                                                 double* __restrict__ partials) {
    __shared__ float wpad[80];   // wpad[p] = win[p-9], zero elsewhere
    __shared__ float gn[TRUNC];

    const int b   = blockIdx.x;
    const int tid = threadIdx.x;  // 64 threads = 1 wave

    const int ts  = max(0, w_end[b] + OFFSET_D - WIN);
    const int len = lengths[b];
    const int te  = min(ts + WIN, len);
    const int Lw  = te - ts;
    const int tg  = tgt[b];

    // wave-parallel normalized truncated Gaussian (f32)
    float g = 0.0f;
    if (tid < TRUNC) {
        const float x = (tid - 10) * (1.0f / 9.0f);
        g = __expf(-0.5f * x * x);
    }
    float gs = g;
    #pragma unroll
    for (int off = 32; off > 0; off >>= 1) gs += __shfl_down(gs, off);
    gs = __shfl(gs, 0);

    wpad[tid] = 0.0f;
    if (tid < 16) wpad[64 + tid] = 0.0f;
    if (tid < TRUNC) gn[tid] = g / gs;
    __syncthreads();

    float sub = 0.0f;
    if (tid < WIN) {
        const float xw = X[(size_t)b * TK + (size_t)(ts + tid) * KK + tg];
        if (tid < Lw) {
            wpad[9 + tid] = xw;   // zero-padded ragged window
            sub = -__logf(fminf(fmaxf(1.0f - xw, EPS), 1.0f));
        }
    }
    __syncthreads();

    float cand = 0.0f;
    if (tid < WIN) {
        float s = 0.0f;
        #pragma unroll
        for (int u = 0; u < TRUNC; ++u) s += gn[u] * wpad[tid + u];
        s = fminf(fmaxf(s, EPS), 1.0f);
        cand = (tid < Lw) ? s : 0.0f;   // exclude out-of-window positions from max
    }

    #pragma unroll
    for (int off = 32; off > 0; off >>= 1) {
        sub += __shfl_down(sub, off);
        cand = fmaxf(cand, __shfl_down(cand, off));
    }
    if (tid == 0) {
        const float pos = -__logf(cand);
        partials[NB1 + b] = (double)(pos - sub);
    }
}

// ---------------- kernel 3: reduce all partials -> scalar
__global__ __launch_bounds__(256) void finalize_kernel(const double* __restrict__ p,
                                                       float* __restrict__ out) {
    double s = 0.0;
    for (int i = threadIdx.x; i < NPART; i += 256) s += p[i];
    #pragma unroll
    for (int off = 32; off > 0; off >>= 1) s += __shfl_down(s, off);
    __shared__ double wsum[4];
    if ((threadIdx.x & 63) == 0) wsum[threadIdx.x >> 6] = s;
    __syncthreads();
    if (threadIdx.x == 0)
        out[0] = (float)(wsum[0] + wsum[1] + wsum[2] + wsum[3]);
}

extern "C" void kernel_launch(void* const* d_in, const int* in_sizes, int n_in,
                              void* d_out, int out_size, void* d_ws, size_t ws_size,
                              hipStream_t stream) {
    const float* X       = (const float*)d_in[0];
    const int*   lengths = (const int*)d_in[1];
    const int*   tgt     = (const int*)d_in[2];
    const int*   w_end   = (const int*)d_in[3];
    float*       out     = (float*)d_out;
    double*      partials = (double*)d_ws;   // NPART doubles = 26.1 KB

    neg_sum_kernel<<<NB1, 256, 0, stream>>>(X, lengths, partials);
    pos_kernel<<<BB, 64, 0, stream>>>(X, lengths, tgt, w_end, partials);
    finalize_kernel<<<1, 256, 0, stream>>>(partials, out);
}

// Round 3
// 153.577 us; speedup vs baseline: 1.5977x; 1.0304x over previous
//
#include <hip/hip_runtime.h>

#define WIN      60
#define OFFSET_D 40
#define TRUNC    21
#define EPS      1e-8f
#define BB       64
#define TT       4000
#define KK       100
#define TK       (TT*KK)          // 400000 elements per batch
#define CH       50               // chunks per batch
#define CHUNK    (TK/CH)          // 8000 elements
#define NB1      (BB*CH)          // 3200 neg partial slots
#define NPART    (NB1 + BB)       // + 64 pos slots

// ---- fused kernel: blocks [0,NB1) do the masked neg-sum over one contiguous
// chunk; blocks [NB1, NB1+BB) do the per-batch positive term (1 wave, no LDS).
__global__ __launch_bounds__(256) void fused_kernel(const float* __restrict__ X,
                                                    const int* __restrict__ lengths,
                                                    const int* __restrict__ tgt,
                                                    const int* __restrict__ w_end,
                                                    double* __restrict__ partials) {
    const int bid = blockIdx.x;

    if (bid < NB1) {
        // ---------------- negative term chunk ----------------
        const int b    = bid / CH;
        const int c    = bid - b * CH;
        const int s    = c * CHUNK;
        const int lenK = lengths[b] * KK;        // always a multiple of 4
        const int e    = min(s + CHUNK, lenK);

        const float* __restrict__ base = X + (size_t)b * TK;
        float a0 = 0.f, a1 = 0.f, a2 = 0.f, a3 = 0.f;

        #pragma unroll 4
        for (int m = s + (threadIdx.x << 2); m < e; m += 256 * 4) {
            const float4 v = *reinterpret_cast<const float4*>(base + m);
            a0 -= __logf(fminf(fmaxf(1.0f - v.x, EPS), 1.0f));
            a1 -= __logf(fminf(fmaxf(1.0f - v.y, EPS), 1.0f));
            a2 -= __logf(fminf(fmaxf(1.0f - v.z, EPS), 1.0f));
            a3 -= __logf(fminf(fmaxf(1.0f - v.w, EPS), 1.0f));
        }
        float local = (a0 + a1) + (a2 + a3);

        #pragma unroll
        for (int off = 32; off > 0; off >>= 1) local += __shfl_down(local, off);
        __shared__ float wsum[4];
        if ((threadIdx.x & 63) == 0) wsum[threadIdx.x >> 6] = local;
        __syncthreads();
        if (threadIdx.x == 0)
            partials[bid] = (double)(wsum[0] + wsum[1] + wsum[2] + wsum[3]);
        return;
    }

    // ---------------- positive term: one wave per batch, shuffle-only ----------------
    if (threadIdx.x >= 64) return;              // single wave; no barriers below
    const int b   = bid - NB1;
    const int tid = threadIdx.x;

    const int ts = max(0, w_end[b] + OFFSET_D - WIN);
    const int te = min(ts + WIN, lengths[b]);
    const int Lw = te - ts;                     // >= 21 always
    const int tg = tgt[b];

    // normalized truncated Gaussian: lane u (<21) holds gn[u]
    float g = 0.0f;
    if (tid < TRUNC) {
        const float x = (tid - 10) * (1.0f / 9.0f);
        g = __expf(-0.5f * x * x);
    }
    float gs = g;
    #pragma unroll
    for (int off = 32; off > 0; off >>= 1) gs += __shfl_down(gs, off);
    gs = __shfl(gs, 0);
    const float gnorm = g / gs;

    // ragged zero-padded window + subtraction term
    float w = 0.0f, sub = 0.0f;
    if (tid < Lw) {                             // Lw <= 60 < 64
        const float xw = X[(size_t)b * TK + (size_t)(ts + tid) * KK + tg];
        w = xw;
        sub = -__logf(fminf(fmaxf(1.0f - xw, EPS), 1.0f));
    }

    // 'same' conv: smoothed[i] = sum_u gn[u] * win[i-9+u]
    float sm = 0.0f;
    #pragma unroll
    for (int u = 0; u < TRUNC; ++u) {
        const float gu = __shfl(gnorm, u);
        const int   j  = tid - 9 + u;
        const float wv = __shfl(w, j & 63);
        sm += gu * (((unsigned)j < (unsigned)WIN) ? wv : 0.0f);  // w already 0 for j>=Lw
    }

    float cand = (tid < Lw) ? fminf(fmaxf(sm, EPS), 1.0f) : 0.0f;
    #pragma unroll
    for (int off = 32; off > 0; off >>= 1) {
        sub  += __shfl_down(sub, off);
        cand  = fmaxf(cand, __shfl_down(cand, off));
    }
    if (tid == 0)
        partials[NB1 + b] = (double)(-__logf(cand) - sub);
}

// ---- finalize: deterministic reduce of all partials -> scalar
__global__ __launch_bounds__(256) void finalize_kernel(const double* __restrict__ p,
                                                       float* __restrict__ out) {
    double s = 0.0;
    for (int i = threadIdx.x; i < NPART; i += 256) s += p[i];
    #pragma unroll
    for (int off = 32; off > 0; off >>= 1) s += __shfl_down(s, off);
    __shared__ double wsum[4];
    if ((threadIdx.x & 63) == 0) wsum[threadIdx.x >> 6] = s;
    __syncthreads();
    if (threadIdx.x == 0)
        out[0] = (float)(wsum[0] + wsum[1] + wsum[2] + wsum[3]);
}

extern "C" void kernel_launch(void* const* d_in, const int* in_sizes, int n_in,
                              void* d_out, int out_size, void* d_ws, size_t ws_size,
                              hipStream_t stream) {
    const float* X        = (const float*)d_in[0];
    const int*   lengths  = (const int*)d_in[1];
    const int*   tgt      = (const int*)d_in[2];
    const int*   w_end    = (const int*)d_in[3];
    float*       out      = (float*)d_out;
    double*      partials = (double*)d_ws;     // NPART doubles = 26.1 KB

    fused_kernel<<<NB1 + BB, 256, 0, stream>>>(X, lengths, tgt, w_end, partials);
    finalize_kernel<<<1, 256, 0, stream>>>(partials, out);
}

// Round 4
// 152.067 us; speedup vs baseline: 1.6135x; 1.0099x over previous
//
#include <hip/hip_runtime.h>

#define WIN      60
#define OFFSET_D 40
#define TRUNC    21
#define EPS      1e-8f
#define BB       64
#define TT       4000
#define KK       100
#define TK       (TT*KK)          // 400000 elements per batch
#define CHUNK    8192             // elements per neg block = 256 threads * 4 * 8 (exact)
#define CHB      49               // ceil(TK/CHUNK); last chunk has 6784 elements
#define NPART    (BB + BB*CHB)    // 64 pos slots + 3136 neg slots = 3200

__device__ __forceinline__ float clamp1(float x) {
    return fminf(fmaxf(1.0f - x, EPS), 1.0f);
}

// blocks [0,BB): positive term (1 wave, shuffle-only).
// blocks [BB, BB+BB*CHB): negative-term chunk; full chunks take a fully
// unrolled 8-load path (8 outstanding float4 loads/wave), boundary chunks a
// dynamic path. Every block writes exactly partials[blockIdx.x].
__global__ __launch_bounds__(256) void fused_kernel(const float* __restrict__ X,
                                                    const int* __restrict__ lengths,
                                                    const int* __restrict__ tgt,
                                                    const int* __restrict__ w_end,
                                                    double* __restrict__ partials) {
    const int bid = blockIdx.x;

    if (bid >= BB) {
        // ---------------- negative term chunk ----------------
        const int nb   = bid - BB;
        const int b    = nb / CHB;
        const int c    = nb - b * CHB;
        const int s    = c * CHUNK;
        const int lenK = lengths[b] * KK;       // multiple of 4 (KK=100)
        const float* __restrict__ base = X + (size_t)b * TK;

        float a0 = 0.f, a1 = 0.f, a2 = 0.f, a3 = 0.f;

        if (s + CHUNK <= lenK) {
            // fully-valid chunk: compile-time trip count, 8 loads in flight
            const float* __restrict__ p = base + s + (threadIdx.x << 2);
            float4 v[8];
            #pragma unroll
            for (int k = 0; k < 8; ++k)
                v[k] = *reinterpret_cast<const float4*>(p + k * 1024);
            #pragma unroll
            for (int k = 0; k < 8; ++k) {
                const float pr = (clamp1(v[k].x) * clamp1(v[k].y)) *
                                 (clamp1(v[k].z) * clamp1(v[k].w));
                ((k & 3) == 0 ? a0 : (k & 3) == 1 ? a1 : (k & 3) == 2 ? a2 : a3)
                    -= __logf(pr);
            }
        } else if (s < lenK) {
            // boundary chunk (or short tail chunk)
            const int e = min(s + CHUNK, lenK);
            for (int m = s + (threadIdx.x << 2); m < e; m += 256 * 4) {
                const float4 v = *reinterpret_cast<const float4*>(base + m);
                const float pr = (clamp1(v.x) * clamp1(v.y)) *
                                 (clamp1(v.z) * clamp1(v.w));
                a0 -= __logf(pr);
            }
        }
        float local = (a0 + a1) + (a2 + a3);

        #pragma unroll
        for (int off = 32; off > 0; off >>= 1) local += __shfl_down(local, off);
        __shared__ float wsum[4];
        if ((threadIdx.x & 63) == 0) wsum[threadIdx.x >> 6] = local;
        __syncthreads();
        if (threadIdx.x == 0)
            partials[bid] = (double)(wsum[0] + wsum[1] + wsum[2] + wsum[3]);
        return;
    }

    // ---------------- positive term: one wave per batch, shuffle-only ----------------
    if (threadIdx.x >= 64) return;              // single wave; no barriers below
    const int b   = bid;
    const int tid = threadIdx.x;

    const int ts = max(0, w_end[b] + OFFSET_D - WIN);
    const int te = min(ts + WIN, lengths[b]);
    const int Lw = te - ts;                     // >= 21 always
    const int tg = tgt[b];

    // normalized truncated Gaussian: lane u (<21) holds gn[u]
    float g = 0.0f;
    if (tid < TRUNC) {
        const float x = (tid - 10) * (1.0f / 9.0f);
        g = __expf(-0.5f * x * x);
    }
    float gs = g;
    #pragma unroll
    for (int off = 32; off > 0; off >>= 1) gs += __shfl_down(gs, off);
    gs = __shfl(gs, 0);
    const float gnorm = g / gs;

    // ragged zero-padded window + subtraction term
    float w = 0.0f, sub = 0.0f;
    if (tid < Lw) {                             // Lw <= 60 < 64
        const float xw = X[(size_t)b * TK + (size_t)(ts + tid) * KK + tg];
        w = xw;
        sub = -__logf(clamp1(xw));
    }

    // 'same' conv: smoothed[i] = sum_u gn[u] * win[i-9+u]
    float sm = 0.0f;
    #pragma unroll
    for (int u = 0; u < TRUNC; ++u) {
        const float gu = __shfl(gnorm, u);
        const int   j  = tid - 9 + u;
        const float wv = __shfl(w, j & 63);
        sm += gu * (((unsigned)j < (unsigned)WIN) ? wv : 0.0f);  // w already 0 for j>=Lw
    }

    float cand = (tid < Lw) ? fminf(fmaxf(sm, EPS), 1.0f) : 0.0f;
    #pragma unroll
    for (int off = 32; off > 0; off >>= 1) {
        sub  += __shfl_down(sub, off);
        cand  = fmaxf(cand, __shfl_down(cand, off));
    }
    if (tid == 0)
        partials[bid] = (double)(-__logf(cand) - sub);
}

// ---- finalize: deterministic reduce of all partials -> scalar
__global__ __launch_bounds__(256) void finalize_kernel(const double* __restrict__ p,
                                                       float* __restrict__ out) {
    double s = 0.0;
    for (int i = threadIdx.x; i < NPART; i += 256) s += p[i];
    #pragma unroll
    for (int off = 32; off > 0; off >>= 1) s += __shfl_down(s, off);
    __shared__ double wsum[4];
    if ((threadIdx.x & 63) == 0) wsum[threadIdx.x >> 6] = s;
    __syncthreads();
    if (threadIdx.x == 0)
        out[0] = (float)(wsum[0] + wsum[1] + wsum[2] + wsum[3]);
}

extern "C" void kernel_launch(void* const* d_in, const int* in_sizes, int n_in,
                              void* d_out, int out_size, void* d_ws, size_t ws_size,
                              hipStream_t stream) {
    const float* X        = (const float*)d_in[0];
    const int*   lengths  = (const int*)d_in[1];
    const int*   tgt      = (const int*)d_in[2];
    const int*   w_end    = (const int*)d_in[3];
    float*       out      = (float*)d_out;
    double*      partials = (double*)d_ws;     // NPART doubles = 25.6 KB

    fused_kernel<<<BB + BB * CHB, 256, 0, stream>>>(X, lengths, tgt, w_end, partials);
    finalize_kernel<<<1, 256, 0, stream>>>(partials, out);
}

// Round 5
// 150.772 us; speedup vs baseline: 1.6274x; 1.0086x over previous
//
#include <hip/hip_runtime.h>

#define WIN      60
#define OFFSET_D 40
#define TRUNC    21
#define EPS      1e-8f
#define BB       64
#define TT       4000
#define KK       100
#define TK       (TT*KK)          // 400000 elements per batch
#define CHUNK    12288            // 256 threads * 4 * 12
#define CHB      33               // ceil(TK/CHUNK); last chunk = 6784 elems
#define NNEG     (BB*CHB)         // 2112 neg blocks
#define NPART    (BB + NNEG)      // + 64 pos slots = 2176

__device__ __forceinline__ float clamp1(float x) {
    return fminf(fmaxf(1.0f - x, EPS), 1.0f);
}

// blocks [0,BB): positive term (1 wave, shuffle-only).
// blocks [BB, BB+NNEG): negative-term chunk. Grid sized so working blocks
// (~1584 after invalid-region skip) fit one residency wave (2048 @ 8 blk/CU).
__global__ __launch_bounds__(256) void fused_kernel(const float* __restrict__ X,
                                                    const int* __restrict__ lengths,
                                                    const int* __restrict__ tgt,
                                                    const int* __restrict__ w_end,
                                                    double* __restrict__ partials) {
    const int bid = blockIdx.x;

    if (bid >= BB) {
        // ---------------- negative term chunk ----------------
        const int nb   = bid - BB;
        const int b    = nb / CHB;
        const int c    = nb - b * CHB;
        const int s    = c * CHUNK;
        const int lenK = lengths[b] * KK;       // multiple of 4 (KK=100)
        const float* __restrict__ base = X + (size_t)b * TK;

        float a0 = 0.f, a1 = 0.f, a2 = 0.f, a3 = 0.f;

        if (s + CHUNK <= lenK) {
            // fully-valid chunk: two phases of {6 float4 loads, compute}
            const float* __restrict__ p = base + s + (threadIdx.x << 2);
            float4 v[6];
            #pragma unroll
            for (int k = 0; k < 6; ++k)
                v[k] = *reinterpret_cast<const float4*>(p + k * 1024);
            #pragma unroll
            for (int k = 0; k < 6; ++k) {
                const float pr = (clamp1(v[k].x) * clamp1(v[k].y)) *
                                 (clamp1(v[k].z) * clamp1(v[k].w));
                ((k & 3) == 0 ? a0 : (k & 3) == 1 ? a1 : (k & 3) == 2 ? a2 : a3)
                    -= __logf(pr);
            }
            #pragma unroll
            for (int k = 0; k < 6; ++k)
                v[k] = *reinterpret_cast<const float4*>(p + (6 + k) * 1024);
            #pragma unroll
            for (int k = 0; k < 6; ++k) {
                const float pr = (clamp1(v[k].x) * clamp1(v[k].y)) *
                                 (clamp1(v[k].z) * clamp1(v[k].w));
                ((k & 3) == 0 ? a1 : (k & 3) == 1 ? a2 : (k & 3) == 2 ? a3 : a0)
                    -= __logf(pr);
            }
        } else if (s < lenK) {
            // boundary chunk: e == lenK here (uniform), per-lane predicated
            const int m0 = s + (threadIdx.x << 2);
            #pragma unroll
            for (int k = 0; k < 12; ++k) {
                const int m = m0 + k * 1024;
                if (m < lenK) {
                    const float4 v = *reinterpret_cast<const float4*>(base + m);
                    const float pr = (clamp1(v.x) * clamp1(v.y)) *
                                     (clamp1(v.z) * clamp1(v.w));
                    a0 -= __logf(pr);
                }
            }
        }
        float local = (a0 + a1) + (a2 + a3);

        #pragma unroll
        for (int off = 32; off > 0; off >>= 1) local += __shfl_down(local, off);
        __shared__ float wsum[4];
        if ((threadIdx.x & 63) == 0) wsum[threadIdx.x >> 6] = local;
        __syncthreads();
        if (threadIdx.x == 0)
            partials[bid] = (double)(wsum[0] + wsum[1] + wsum[2] + wsum[3]);
        return;
    }

    // ---------------- positive term: one wave per batch, shuffle-only ----------------
    if (threadIdx.x >= 64) return;              // single wave; no barriers below
    const int b   = bid;
    const int tid = threadIdx.x;

    const int ts = max(0, w_end[b] + OFFSET_D - WIN);
    const int te = min(ts + WIN, lengths[b]);
    const int Lw = te - ts;                     // >= 21 always
    const int tg = tgt[b];

    // normalized truncated Gaussian: lane u (<21) holds gn[u]
    float g = 0.0f;
    if (tid < TRUNC) {
        const float x = (tid - 10) * (1.0f / 9.0f);
        g = __expf(-0.5f * x * x);
    }
    float gs = g;
    #pragma unroll
    for (int off = 32; off > 0; off >>= 1) gs += __shfl_down(gs, off);
    gs = __shfl(gs, 0);
    const float gnorm = g / gs;

    // ragged zero-padded window + subtraction term
    float w = 0.0f, sub = 0.0f;
    if (tid < Lw) {                             // Lw <= 60 < 64
        const float xw = X[(size_t)b * TK + (size_t)(ts + tid) * KK + tg];
        w = xw;
        sub = -__logf(clamp1(xw));
    }

    // 'same' conv: smoothed[i] = sum_u gn[u] * win[i-9+u]
    float sm = 0.0f;
    #pragma unroll
    for (int u = 0; u < TRUNC; ++u) {
        const float gu = __shfl(gnorm, u);
        const int   j  = tid - 9 + u;
        const float wv = __shfl(w, j & 63);
        sm += gu * (((unsigned)j < (unsigned)WIN) ? wv : 0.0f);  // w already 0 for j>=Lw
    }

    float cand = (tid < Lw) ? fminf(fmaxf(sm, EPS), 1.0f) : 0.0f;
    #pragma unroll
    for (int off = 32; off > 0; off >>= 1) {
        sub  += __shfl_down(sub, off);
        cand  = fmaxf(cand, __shfl_down(cand, off));
    }
    if (tid == 0)
        partials[bid] = (double)(-__logf(cand) - sub);
}

// ---- finalize: deterministic reduce of all partials -> scalar
__global__ __launch_bounds__(256) void finalize_kernel(const double* __restrict__ p,
                                                       float* __restrict__ out) {
    double s = 0.0;
    for (int i = threadIdx.x; i < NPART; i += 256) s += p[i];
    #pragma unroll
    for (int off = 32; off > 0; off >>= 1) s += __shfl_down(s, off);
    __shared__ double wsum[4];
    if ((threadIdx.x & 63) == 0) wsum[threadIdx.x >> 6] = s;
    __syncthreads();
    if (threadIdx.x == 0)
        out[0] = (float)(wsum[0] + wsum[1] + wsum[2] + wsum[3]);
}

extern "C" void kernel_launch(void* const* d_in, const int* in_sizes, int n_in,
                              void* d_out, int out_size, void* d_ws, size_t ws_size,
                              hipStream_t stream) {
    const float* X        = (const float*)d_in[0];
    const int*   lengths  = (const int*)d_in[1];
    const int*   tgt      = (const int*)d_in[2];
    const int*   w_end    = (const int*)d_in[3];
    float*       out      = (float*)d_out;
    double*      partials = (double*)d_ws;     // NPART doubles = 17.4 KB

    fused_kernel<<<BB + NNEG, 256, 0, stream>>>(X, lengths, tgt, w_end, partials);
    finalize_kernel<<<1, 256, 0, stream>>>(partials, out);
}